// Round 2
// baseline (1745.002 us; speedup 1.0000x reference)
//
#include <hip/hip_runtime.h>
#include <hip/hip_bf16.h>

// Problem constants
#define QN    2048
#define NN    100000
#define DD    1024
#define CC    1000
#define KK    50
#define BROWS 100096   // NN padded to multiple of 256
#define NBLK  782      // merge granularity: BROWS / 128
#define BMT   256      // gemm tile M (q rows)
#define BNT   256      // gemm tile N (gallery cols)
#define BKT   32       // k per tile
#define KT    (DD / BKT)     // 32 k-tiles
#define GY    (BROWS / BNT)  // 391

typedef _Float16 f16x8 __attribute__((ext_vector_type(8)));
typedef float f32x4  __attribute__((ext_vector_type(4)));

__device__ __forceinline__ short f2h(float x) {
    _Float16 h = (_Float16)x;                    // RN
    return (short)__builtin_bit_cast(unsigned short, h);
}
__device__ __forceinline__ float h2f(short s) {
    _Float16 h = __builtin_bit_cast(_Float16, (unsigned short)s);
    return (float)h;
}

// ---------------- convert: fp32 -> fp16 hi (+ optional fp16 lo residual) ----------------
__global__ __launch_bounds__(256) void knn_convert(
    const float* __restrict__ src, short* __restrict__ hi, short* __restrict__ lo,
    int rows_valid, int write_lo)
{
    const int n  = blockIdx.x;
    const int k4 = threadIdx.x << 2;
    float4 v = make_float4(0.f, 0.f, 0.f, 0.f);
    if (n < rows_valid)
        v = *reinterpret_cast<const float4*>(&src[(size_t)n * DD + k4]);

    short h0 = f2h(v.x), h1 = f2h(v.y), h2 = f2h(v.z), h3 = f2h(v.w);
    *reinterpret_cast<short4*>(&hi[(size_t)n * DD + k4]) =
        make_short4(h0, h1, h2, h3);
    if (write_lo) {
        short4 lv = make_short4(f2h(v.x - h2f(h0)), f2h(v.y - h2f(h1)),
                                f2h(v.z - h2f(h2)), f2h(v.w - h2f(h3)));
        *reinterpret_cast<short4*>(&lo[(size_t)n * DD + k4]) = lv;
    }
}

// ---------------- MFMA GEMM, 256x256 tile, 3-deep ring pipeline ----------------
// 8 waves (2M x 4N), per-wave 128x64 output = acc[8][4] of 16x16 frags.
// 3 streams staged per K-tile (Ahi, Alo, Bhi), BK=32 -> 16KB each, 48KB/tile,
// 3-slot ring = 144KB LDS. Loads for tile t+2 issued at tile t start;
// counted s_waitcnt vmcnt(6) at tile end (t+1 complete, t+2 in flight) + raw
// s_barrier — never drains to 0 in the main loop (T3+T4).
// Chunk-XOR LDS swizzle as before: slot chunk cs holds data chunk cs^((row>>1)&3).
#define GL(gptr, ldsptr) __builtin_amdgcn_global_load_lds(                    \
    (const __attribute__((address_space(1))) void*)(gptr),                    \
    (__attribute__((address_space(3))) void*)(ldsptr), 16, 0, 0)

__global__ __launch_bounds__(512, 2) void knn_gemm(
    const short* __restrict__ Ahi, const short* __restrict__ Alo,
    const short* __restrict__ Bhi,
    float* __restrict__ out, float* __restrict__ bm_s, int* __restrict__ bm_i)
{
    __shared__ short ring[3][3][256][32];   // [slot][stream 0=Ahi,1=Alo,2=B][row][k]
    __shared__ float red_s[4][256];
    __shared__ int   red_i[4][256];

    const int tid  = threadIdx.x;
    const int lane = tid & 63;
    const int w    = tid >> 6;           // 0..7
    const int wm   = (w >> 2) * 128;     // wave M offset
    const int wn   = (w & 3) * 64;       // wave N offset

    // bijective XCD swizzle: 3128 blocks = 8 XCDs * 391; XCD k gets a
    // contiguous band of c-panels (vy) with all q-slices (vx) -> B L2 reuse.
    const int lin = (int)blockIdx.x + 8 * (int)blockIdx.y;   // gridDim.x == 8
    const int g   = (lin & 7) * GY + (lin >> 3);
    const int vx  = g & 7;
    const int vy  = g >> 3;
    const int q0  = vx * BMT;
    const int c0  = vy * BNT;

    const int srow = w * 16 + (lane >> 2);                    // staging row 0..127 (+128 for GL#2)
    const int kb   = (((lane & 3) ^ ((lane >> 3) & 3)) * 16); // swizzled source chunk bytes
    const int fr   = lane & 15;
    const int fq   = lane >> 4;
    const int cx   = (fq ^ ((fr >> 1) & 3)) * 8;              // swizzled read chunk (shorts)

    f32x4 acc[8][4];
    #pragma unroll
    for (int i = 0; i < 8; ++i)
        #pragma unroll
        for (int j = 0; j < 4; ++j)
            acc[i][j] = (f32x4){0.f, 0.f, 0.f, 0.f};

    const size_t rowb = (size_t)DD * 2;
    const size_t gA   = (size_t)(q0 + srow) * rowb + kb;
    const size_t gA2  = gA + 128 * rowb;
    const size_t gB   = (size_t)(c0 + srow) * rowb + kb;
    const size_t gB2  = gB + 128 * rowb;
    char* ringc      = (char*)&ring[0][0][0][0];
    const int  w16b  = (w * 16) * 64;    // wave-uniform LDS staging byte offset

#define STAGE(t2, sl) do {                                                    \
    const size_t ko = (size_t)(t2) * (BKT * 2);                               \
    char* LA = ringc + ((sl) * 3 + 0) * (256 * 64) + w16b;                    \
    char* LL = ringc + ((sl) * 3 + 1) * (256 * 64) + w16b;                    \
    char* LB = ringc + ((sl) * 3 + 2) * (256 * 64) + w16b;                    \
    GL((const char*)Ahi + gA  + ko, LA);                                      \
    GL((const char*)Ahi + gA2 + ko, LA + 128 * 64);                           \
    GL((const char*)Alo + gA  + ko, LL);                                      \
    GL((const char*)Alo + gA2 + ko, LL + 128 * 64);                           \
    GL((const char*)Bhi + gB  + ko, LB);                                      \
    GL((const char*)Bhi + gB2 + ko, LB + 128 * 64);                           \
} while (0)

    // prologue: tiles 0,1 staged; wait tile0 (6 newest = tile1 stay in flight)
    STAGE(0, 0);
    STAGE(1, 1);
    asm volatile("s_waitcnt vmcnt(6)" ::: "memory");
    __builtin_amdgcn_s_barrier();
    __builtin_amdgcn_sched_barrier(0);

    int slot = 0;
    for (int t = 0; t < KT; ++t) {
        if (t + 2 < KT) {
            const int s2 = (slot + 2 >= 3) ? slot - 1 : slot + 2;
            STAGE(t + 2, s2);
        }
        const short (*Ahs)[32] = ring[slot][0];
        const short (*Als)[32] = ring[slot][1];
        const short (*Bhs)[32] = ring[slot][2];

        f16x8 bh[4];
        #pragma unroll
        for (int j = 0; j < 4; ++j)
            bh[j] = *reinterpret_cast<const f16x8*>(&Bhs[wn + j * 16 + fr][cx]);

        f16x8 ah[8], al[8];
        #pragma unroll
        for (int p = 0; p < 4; ++p) {
            const int i0 = 2 * p, i1 = 2 * p + 1;
            ah[i0] = *reinterpret_cast<const f16x8*>(&Ahs[wm + i0 * 16 + fr][cx]);
            ah[i1] = *reinterpret_cast<const f16x8*>(&Ahs[wm + i1 * 16 + fr][cx]);
            al[i0] = *reinterpret_cast<const f16x8*>(&Als[wm + i0 * 16 + fr][cx]);
            al[i1] = *reinterpret_cast<const f16x8*>(&Als[wm + i1 * 16 + fr][cx]);
            __builtin_amdgcn_s_setprio(1);
            #pragma unroll
            for (int j = 0; j < 4; ++j) {
                acc[i0][j] = __builtin_amdgcn_mfma_f32_16x16x32_f16(ah[i0], bh[j], acc[i0][j], 0, 0, 0);
                acc[i0][j] = __builtin_amdgcn_mfma_f32_16x16x32_f16(al[i0], bh[j], acc[i0][j], 0, 0, 0);
                acc[i1][j] = __builtin_amdgcn_mfma_f32_16x16x32_f16(ah[i1], bh[j], acc[i1][j], 0, 0, 0);
                acc[i1][j] = __builtin_amdgcn_mfma_f32_16x16x32_f16(al[i1], bh[j], acc[i1][j], 0, 0, 0);
            }
            __builtin_amdgcn_s_setprio(0);
        }

        __builtin_amdgcn_sched_barrier(0);
        if (t + 2 < KT)       asm volatile("s_waitcnt vmcnt(6)" ::: "memory");
        else if (t + 1 < KT)  asm volatile("s_waitcnt vmcnt(0)" ::: "memory");
        __builtin_amdgcn_s_barrier();
        __builtin_amdgcn_sched_barrier(0);
        slot = (slot + 1 >= 3) ? 0 : slot + 1;
    }
#undef STAGE

    // epilogue: D layout col=lane&15, row=(lane>>4)*4+reg  [m89-verified]
    // scores write (padded cols -> -1e30) + per-row max at 128-col granularity
    #pragma unroll
    for (int i = 0; i < 8; ++i) {
        const int lrow = wm + i * 16 + fq * 4;   // +r
        const int qrow = q0 + lrow;
        float rv[4]; int rc[4];
        #pragma unroll
        for (int r = 0; r < 4; ++r) { rv[r] = -3e30f; rc[r] = 0; }
        #pragma unroll
        for (int j = 0; j < 4; ++j) {
            const int col = c0 + wn + j * 16 + fr;
            const bool ok = (col < NN);
            float* dst = &out[(size_t)qrow * BROWS + col];
            #pragma unroll
            for (int r = 0; r < 4; ++r) {
                float v = ok ? acc[i][j][r] : -1e30f;
                dst[r * (size_t)BROWS] = v;
                if (v > rv[r]) { rv[r] = v; rc[r] = col; }   // ascending j: ties keep smaller col
            }
        }
        #pragma unroll
        for (int r = 0; r < 4; ++r) {
            float v = rv[r]; int c = rc[r];
            #pragma unroll
            for (int m = 1; m <= 8; m <<= 1) {               // reduce across fr (16-lane group)
                float ov = __shfl_xor(v, m);
                int   oc = __shfl_xor(c, m);
                if (ov > v || (ov == v && oc < c)) { v = ov; c = oc; }
            }
            if (fr == 0) {
                red_s[w & 3][lrow + r] = v;
                red_i[w & 3][lrow + r] = c;
            }
        }
    }
    __syncthreads();
    {
        // 512 threads: half 0 combines wn-groups {0,1} (cols c0..c0+127) -> bm[2*vy],
        //              half 1 combines {2,3} (cols c0+128..255) -> bm[2*vy+1]
        const int row  = tid & 255;
        const int half = tid >> 8;
        float v0 = red_s[2 * half][row],     v1 = red_s[2 * half + 1][row];
        int   i0 = red_i[2 * half][row],     i1 = red_i[2 * half + 1][row];
        bool take1 = (v1 > v0) || (v1 == v0 && i1 < i0);
        bm_s[(size_t)(q0 + row) * NBLK + vy * 2 + half] = take1 ? v1 : v0;
        bm_i[(size_t)(q0 + row) * NBLK + vy * 2 + half] = take1 ? i1 : i0;
    }
}

// ---------------- merge: per-query top-50 from 782 block maxima ----------------
__global__ __launch_bounds__(64) void knn_merge(
    float* __restrict__ sc,
    const float* __restrict__ bm_s, const int* __restrict__ bm_i,
    float* __restrict__ top_s, int* __restrict__ top_i)
{
    const int q = blockIdx.x;
    const int t = threadIdx.x;

    __shared__ float pool_s[NBLK];
    __shared__ int   pool_i[NBLK];
    __shared__ float win_s[KK];
    __shared__ int   win_i[KK];

    float* row = sc + (size_t)q * BROWS;

    for (int e = t; e < NBLK; e += 64) {
        pool_s[e] = bm_s[(size_t)q * NBLK + e];
        pool_i[e] = bm_i[(size_t)q * NBLK + e];
    }
    __syncthreads();

    for (int r = 0; r < KK; ++r) {
        float bs = -3e30f; int be = 0;
        for (int e = t; e < NBLK; e += 64) {
            float v = pool_s[e];
            if (v > bs) { bs = v; be = e; }
        }
        #pragma unroll
        for (int m = 32; m; m >>= 1) {
            float ov = __shfl_xor(bs, m);
            int   oe = __shfl_xor(be, m);
            if (ov > bs || (ov == bs && oe < be)) { bs = ov; be = oe; }
        }
        if (t == 0) {
            win_s[r] = bs;
            win_i[r] = pool_i[be];
            row[pool_i[be]] = -1e30f;            // mark taken
        }
        __syncthreads();

        {   // rescan winning 128-col slice
            const int base = be * 128;
            float v0 = row[base + t], v1 = row[base + 64 + t];
            int   i0 = base + t,      i1 = base + 64 + t;
            if (v1 > v0) { v0 = v1; i0 = i1; }
            #pragma unroll
            for (int m = 32; m; m >>= 1) {
                float ov = __shfl_xor(v0, m);
                int   oi = __shfl_xor(i0, m);
                if (ov > v0 || (ov == v0 && oi < i0)) { v0 = ov; i0 = oi; }
            }
            if (t == 0) { pool_s[be] = v0; pool_i[be] = i0; }
        }
        __syncthreads();
    }

    if (t < KK) { top_s[q * 64 + t] = win_s[t]; top_i[q * 64 + t] = win_i[t]; }
    else        { top_s[q * 64 + t] = -1e30f;   top_i[q * 64 + t] = 0; }
}

// ---------------- vote: class histogram, normalize, write preds + targets ----------------
__global__ __launch_bounds__(256) void knn_vote(
    const float* __restrict__ top_s, const int* __restrict__ top_i,
    const int* __restrict__ labels, const int* __restrict__ targets,
    float* __restrict__ out)
{
    const int q = blockIdx.x;
    const int t = threadIdx.x;
    __shared__ float hist[CC];
    __shared__ float ssum;

    for (int c = t; c < CC; c += 256) hist[c] = 0.f;
    if (t == 0) ssum = 0.f;
    __syncthreads();

    if (t < KK) {
        float s = top_s[q * 64 + t];
        int   idx = top_i[q * 64 + t];
        if (s > -1e29f) {
            int lab = labels[idx];
            atomicAdd(&hist[lab], s);
            atomicAdd(&ssum, s);
        }
    }
    __syncthreads();

    float denom = ssum;
    if (denom == 0.f) denom = 1.f;
    float inv = 1.f / denom;
    for (int c = t; c < CC; c += 256)
        out[(size_t)q * CC + c] = hist[c] * inv;
    if (t == 0)
        out[(size_t)QN * CC + q] = (float)targets[q];
}

// ---------------- host launch ----------------
extern "C" void kernel_launch(void* const* d_in, const int* in_sizes, int n_in,
                              void* d_out, int out_size, void* d_ws, size_t ws_size,
                              hipStream_t stream) {
    const float* samples = (const float*)d_in[0];   // [QN][DD]
    const int*   targets = (const int*)d_in[1];     // [QN]
    const float* train   = (const float*)d_in[2];   // [NN][DD]
    const int*   labels  = (const int*)d_in[3];     // [NN]
    float* out = (float*)d_out;

    char* ws = (char*)d_ws;
    short* Ahi = (short*)ws;                                     // 4MB
    short* Alo = Ahi + (size_t)QN * DD;                          // 4MB
    short* Bhi = (short*)(ws + (16 << 20));                      // 195.5MB
    size_t bm_off = (size_t)(16 << 20) + 2 * (size_t)BROWS * DD * 2;
    float* bm_s = (float*)(ws + bm_off);                         // ≈ 6.1MB
    int*   bm_i = (int*)(ws + bm_off + (8 << 20));               // ≈ 6.1MB
    float* top_s = (float*)(ws + bm_off + (16 << 20));           // 512KB
    int*   top_i = (int*)(ws + bm_off + (17 << 20));             // 512KB
    float* scores = (float*)(ws + bm_off + (18 << 20));          // ≈ 820MB

    knn_convert<<<QN,    256, 0, stream>>>(samples, Ahi, Alo, QN, 1);
    knn_convert<<<BROWS, 256, 0, stream>>>(train,   Bhi, nullptr, NN, 0);

    dim3 grid(QN / BMT, GY);    // (8, 391); swizzle in-kernel maps to XCD bands
    knn_gemm<<<grid, 512, 0, stream>>>(Ahi, Alo, Bhi, scores, bm_s, bm_i);

    knn_merge<<<QN, 64, 0, stream>>>(scores, bm_s, bm_i, top_s, top_i);
    knn_vote<<<QN, 256, 0, stream>>>(top_s, top_i, labels, targets, out);
}

// Round 3
// 1612.772 us; speedup vs baseline: 1.0820x; 1.0820x over previous
//
#include <hip/hip_runtime.h>
#include <hip/hip_bf16.h>

// Problem constants
#define QN    2048
#define NN    100000
#define DD    1024
#define CC    1000
#define KK    50
#define BROWS 100096   // NN padded to multiple of 256
#define NBLK  782      // merge granularity: BROWS / 128
#define BMT   256      // gemm tile M (q rows)
#define BNT   256      // gemm tile N (gallery cols)
#define BKT   32       // k per tile
#define KT    (DD / BKT)     // 32 k-tiles
#define GY    (BROWS / BNT)  // 391

typedef _Float16 f16x8 __attribute__((ext_vector_type(8)));
typedef float f32x4  __attribute__((ext_vector_type(4)));

__device__ __forceinline__ short f2h(float x) {
    _Float16 h = (_Float16)x;                    // RN
    return (short)__builtin_bit_cast(unsigned short, h);
}
__device__ __forceinline__ float h2f(short s) {
    _Float16 h = __builtin_bit_cast(_Float16, (unsigned short)s);
    return (float)h;
}

// ---------------- convert: fp32 -> fp16 hi (+ optional fp16 lo residual) ----------------
__global__ __launch_bounds__(256) void knn_convert(
    const float* __restrict__ src, short* __restrict__ hi, short* __restrict__ lo,
    int rows_valid, int write_lo)
{
    const int n  = blockIdx.x;
    const int k4 = threadIdx.x << 2;
    float4 v = make_float4(0.f, 0.f, 0.f, 0.f);
    if (n < rows_valid)
        v = *reinterpret_cast<const float4*>(&src[(size_t)n * DD + k4]);

    short h0 = f2h(v.x), h1 = f2h(v.y), h2 = f2h(v.z), h3 = f2h(v.w);
    *reinterpret_cast<short4*>(&hi[(size_t)n * DD + k4]) =
        make_short4(h0, h1, h2, h3);
    if (write_lo) {
        short4 lv = make_short4(f2h(v.x - h2f(h0)), f2h(v.y - h2f(h1)),
                                f2h(v.z - h2f(h2)), f2h(v.w - h2f(h3)));
        *reinterpret_cast<short4*>(&lo[(size_t)n * DD + k4]) = lv;
    }
}

// ---------------- MFMA GEMM, 256x256 tile, 3-ring + 4-phase interleave ----------------
// 8 waves (2M x 4N), per-wave 128x64 output = acc[8][4] of 16x16 frags.
// Per K-tile (BK=32): 4 phases x {ds_read subtile | issue 2 GLs for tile t+2 |
//   s_barrier | lgkmcnt(0)+sched_barrier | setprio(1) 16 MFMA setprio(0) | s_barrier}.
// Counted s_waitcnt vmcnt(6) ONCE per tile (t+1 retired, t+2 in flight) — never
// drained to 0 in steady state (T3+T4). Chunk-XOR LDS swizzle as before.
#define GL(gptr, ldsptr) __builtin_amdgcn_global_load_lds(                    \
    (const __attribute__((address_space(1))) void*)(gptr),                    \
    (__attribute__((address_space(3))) void*)(ldsptr), 16, 0, 0)

__global__ __launch_bounds__(512, 2) void knn_gemm(
    const short* __restrict__ Ahi, const short* __restrict__ Alo,
    const short* __restrict__ Bhi,
    float* __restrict__ out, float* __restrict__ bm_s, int* __restrict__ bm_i)
{
    __shared__ short ring[3][3][256][32];   // [slot][stream 0=Ahi,1=Alo,2=B][row][k]
    __shared__ float red_s[4][256];
    __shared__ int   red_i[4][256];

    const int tid  = threadIdx.x;
    const int lane = tid & 63;
    const int w    = tid >> 6;           // 0..7
    const int wm   = (w >> 2) * 128;     // wave M offset
    const int wn   = (w & 3) * 64;       // wave N offset

    // bijective XCD swizzle: 3128 blocks = 8 XCDs * 391; XCD k gets a
    // contiguous band of c-panels (vy) with all q-slices (vx) -> B L2 reuse.
    const int lin = (int)blockIdx.x + 8 * (int)blockIdx.y;   // gridDim.x == 8
    const int g   = (lin & 7) * GY + (lin >> 3);
    const int vx  = g & 7;
    const int vy  = g >> 3;
    const int q0  = vx * BMT;
    const int c0  = vy * BNT;

    const int srow = w * 16 + (lane >> 2);                    // staging row 0..127 (+128 for GL#2)
    const int kb   = (((lane & 3) ^ ((lane >> 3) & 3)) * 16); // swizzled source chunk bytes
    const int fr   = lane & 15;
    const int fq   = lane >> 4;
    const int cx   = (fq ^ ((fr >> 1) & 3)) * 8;              // swizzled read chunk (shorts)

    f32x4 acc[8][4];
    #pragma unroll
    for (int i = 0; i < 8; ++i)
        #pragma unroll
        for (int j = 0; j < 4; ++j)
            acc[i][j] = (f32x4){0.f, 0.f, 0.f, 0.f};

    const size_t rowb = (size_t)DD * 2;
    const size_t gA   = (size_t)(q0 + srow) * rowb + kb;
    const size_t gA2  = gA + 128 * rowb;
    const size_t gB   = (size_t)(c0 + srow) * rowb + kb;
    const size_t gB2  = gB + 128 * rowb;
    char* ringc      = (char*)&ring[0][0][0][0];
    const int  w16b  = (w * 16) * 64;    // wave-uniform LDS staging byte offset

#define STAGE_A(t2, sl) do {                                                  \
    const size_t ko = (size_t)(t2) * (BKT * 2);                               \
    char* L = ringc + ((sl) * 3 + 0) * (256 * 64) + w16b;                     \
    GL((const char*)Ahi + gA  + ko, L);                                       \
    GL((const char*)Ahi + gA2 + ko, L + 128 * 64);                            \
} while (0)
#define STAGE_L(t2, sl) do {                                                  \
    const size_t ko = (size_t)(t2) * (BKT * 2);                               \
    char* L = ringc + ((sl) * 3 + 1) * (256 * 64) + w16b;                     \
    GL((const char*)Alo + gA  + ko, L);                                       \
    GL((const char*)Alo + gA2 + ko, L + 128 * 64);                            \
} while (0)
#define STAGE_B(t2, sl) do {                                                  \
    const size_t ko = (size_t)(t2) * (BKT * 2);                               \
    char* L = ringc + ((sl) * 3 + 2) * (256 * 64) + w16b;                     \
    GL((const char*)Bhi + gB  + ko, L);                                       \
    GL((const char*)Bhi + gB2 + ko, L + 128 * 64);                            \
} while (0)

#define DS_A(i) (*reinterpret_cast<const f16x8*>(&Ahs[wm + (i) * 16 + fr][cx]))
#define DS_L(i) (*reinterpret_cast<const f16x8*>(&Als[wm + (i) * 16 + fr][cx]))
#define DS_B(j) (*reinterpret_cast<const f16x8*>(&Bhs[wn + (j) * 16 + fr][cx]))

#define MFMA16(I0, I1, A0, L0, A1, L1)                                        \
    __builtin_amdgcn_s_setprio(1);                                            \
    _Pragma("unroll")                                                         \
    for (int j = 0; j < 4; ++j) {                                             \
        acc[I0][j] = __builtin_amdgcn_mfma_f32_16x16x32_f16(A0, bh[j], acc[I0][j], 0, 0, 0); \
        acc[I0][j] = __builtin_amdgcn_mfma_f32_16x16x32_f16(L0, bh[j], acc[I0][j], 0, 0, 0); \
        acc[I1][j] = __builtin_amdgcn_mfma_f32_16x16x32_f16(A1, bh[j], acc[I1][j], 0, 0, 0); \
        acc[I1][j] = __builtin_amdgcn_mfma_f32_16x16x32_f16(L1, bh[j], acc[I1][j], 0, 0, 0); \
    }                                                                         \
    __builtin_amdgcn_s_setprio(0);

#define PHASE_SYNC_PRE()                                                      \
    __builtin_amdgcn_s_barrier();                                             \
    asm volatile("s_waitcnt lgkmcnt(0)" ::: "memory");                        \
    __builtin_amdgcn_sched_barrier(0);

#define PHASE_SYNC_POST()                                                     \
    __builtin_amdgcn_sched_barrier(0);                                        \
    __builtin_amdgcn_s_barrier();

    // prologue: tiles 0,1 staged; wait tile0 (6 newest = tile1 stay in flight)
    STAGE_A(0, 0); STAGE_L(0, 0); STAGE_B(0, 0);
    STAGE_A(1, 1); STAGE_L(1, 1); STAGE_B(1, 1);
    asm volatile("s_waitcnt vmcnt(6)" ::: "memory");
    __builtin_amdgcn_s_barrier();
    __builtin_amdgcn_sched_barrier(0);

    int slot = 0;
    for (int t = 0; t < KT; ++t) {
        const short (*Ahs)[32] = ring[slot][0];
        const short (*Als)[32] = ring[slot][1];
        const short (*Bhs)[32] = ring[slot][2];
        const int  s2 = (slot + 2 >= 3) ? slot - 1 : slot + 2;
        const bool pf = (t + 2 < KT);

        f16x8 bh[4];
        // ---- phase 0: B frags + A rows 0,1 ---- (8 ds_reads, 2 GLs)
        bh[0] = DS_B(0); bh[1] = DS_B(1); bh[2] = DS_B(2); bh[3] = DS_B(3);
        f16x8 a0 = DS_A(0), l0 = DS_L(0), a1 = DS_A(1), l1 = DS_L(1);
        if (pf) STAGE_A(t + 2, s2);
        PHASE_SYNC_PRE();
        MFMA16(0, 1, a0, l0, a1, l1);
        PHASE_SYNC_POST();

        // ---- phase 1: A rows 2,3 ---- (4 ds_reads, 2 GLs)
        a0 = DS_A(2); l0 = DS_L(2); a1 = DS_A(3); l1 = DS_L(3);
        if (pf) STAGE_L(t + 2, s2);
        PHASE_SYNC_PRE();
        MFMA16(2, 3, a0, l0, a1, l1);
        PHASE_SYNC_POST();

        // ---- phase 2: A rows 4,5 ---- (4 ds_reads, 2 GLs)
        a0 = DS_A(4); l0 = DS_L(4); a1 = DS_A(5); l1 = DS_L(5);
        if (pf) STAGE_B(t + 2, s2);
        PHASE_SYNC_PRE();
        MFMA16(4, 5, a0, l0, a1, l1);
        PHASE_SYNC_POST();

        // ---- phase 3: A rows 6,7 ---- (4 ds_reads, no GL)
        a0 = DS_A(6); l0 = DS_L(6); a1 = DS_A(7); l1 = DS_L(7);
        PHASE_SYNC_PRE();
        MFMA16(6, 7, a0, l0, a1, l1);
        __builtin_amdgcn_sched_barrier(0);

        // ---- tile end: counted wait (never 0 in steady state) ----
        if (pf)                asm volatile("s_waitcnt vmcnt(6)" ::: "memory");
        else if (t + 1 < KT)   asm volatile("s_waitcnt vmcnt(0)" ::: "memory");
        __builtin_amdgcn_s_barrier();
        __builtin_amdgcn_sched_barrier(0);
        slot = (slot + 1 >= 3) ? 0 : slot + 1;
    }
#undef STAGE_A
#undef STAGE_L
#undef STAGE_B

    // epilogue: D layout col=lane&15, row=(lane>>4)*4+reg  [m89-verified]
    // scores write (padded cols -> -1e30) + per-row max at 128-col granularity
    #pragma unroll
    for (int i = 0; i < 8; ++i) {
        const int lrow = wm + i * 16 + fq * 4;   // +r
        const int qrow = q0 + lrow;
        float rv[4]; int rc[4];
        #pragma unroll
        for (int r = 0; r < 4; ++r) { rv[r] = -3e30f; rc[r] = 0; }
        #pragma unroll
        for (int j = 0; j < 4; ++j) {
            const int col = c0 + wn + j * 16 + fr;
            const bool ok = (col < NN);
            float* dst = &out[(size_t)qrow * BROWS + col];
            #pragma unroll
            for (int r = 0; r < 4; ++r) {
                float v = ok ? acc[i][j][r] : -1e30f;
                dst[r * (size_t)BROWS] = v;
                if (v > rv[r]) { rv[r] = v; rc[r] = col; }   // ascending j: ties keep smaller col
            }
        }
        #pragma unroll
        for (int r = 0; r < 4; ++r) {
            float v = rv[r]; int c = rc[r];
            #pragma unroll
            for (int m = 1; m <= 8; m <<= 1) {               // reduce across fr (16-lane group)
                float ov = __shfl_xor(v, m);
                int   oc = __shfl_xor(c, m);
                if (ov > v || (ov == v && oc < c)) { v = ov; c = oc; }
            }
            if (fr == 0) {
                red_s[w & 3][lrow + r] = v;
                red_i[w & 3][lrow + r] = c;
            }
        }
    }
    __syncthreads();
    {
        // 512 threads: half 0 combines wn-groups {0,1} (cols c0..c0+127) -> bm[2*vy],
        //              half 1 combines {2,3} (cols c0+128..255) -> bm[2*vy+1]
        const int row  = tid & 255;
        const int half = tid >> 8;
        float v0 = red_s[2 * half][row],     v1 = red_s[2 * half + 1][row];
        int   i0 = red_i[2 * half][row],     i1 = red_i[2 * half + 1][row];
        bool take1 = (v1 > v0) || (v1 == v0 && i1 < i0);
        bm_s[(size_t)(q0 + row) * NBLK + vy * 2 + half] = take1 ? v1 : v0;
        bm_i[(size_t)(q0 + row) * NBLK + vy * 2 + half] = take1 ? i1 : i0;
    }
}

// ---------------- merge: per-query top-50 from 782 block maxima ----------------
__global__ __launch_bounds__(64) void knn_merge(
    float* __restrict__ sc,
    const float* __restrict__ bm_s, const int* __restrict__ bm_i,
    float* __restrict__ top_s, int* __restrict__ top_i)
{
    const int q = blockIdx.x;
    const int t = threadIdx.x;

    __shared__ float pool_s[NBLK];
    __shared__ int   pool_i[NBLK];
    __shared__ float win_s[KK];
    __shared__ int   win_i[KK];

    float* row = sc + (size_t)q * BROWS;

    for (int e = t; e < NBLK; e += 64) {
        pool_s[e] = bm_s[(size_t)q * NBLK + e];
        pool_i[e] = bm_i[(size_t)q * NBLK + e];
    }
    __syncthreads();

    for (int r = 0; r < KK; ++r) {
        float bs = -3e30f; int be = 0;
        for (int e = t; e < NBLK; e += 64) {
            float v = pool_s[e];
            if (v > bs) { bs = v; be = e; }
        }
        #pragma unroll
        for (int m = 32; m; m >>= 1) {
            float ov = __shfl_xor(bs, m);
            int   oe = __shfl_xor(be, m);
            if (ov > bs || (ov == bs && oe < be)) { bs = ov; be = oe; }
        }
        if (t == 0) {
            win_s[r] = bs;
            win_i[r] = pool_i[be];
            row[pool_i[be]] = -1e30f;            // mark taken
        }
        __syncthreads();

        {   // rescan winning 128-col slice
            const int base = be * 128;
            float v0 = row[base + t], v1 = row[base + 64 + t];
            int   i0 = base + t,      i1 = base + 64 + t;
            if (v1 > v0) { v0 = v1; i0 = i1; }
            #pragma unroll
            for (int m = 32; m; m >>= 1) {
                float ov = __shfl_xor(v0, m);
                int   oi = __shfl_xor(i0, m);
                if (ov > v0 || (ov == v0 && oi < i0)) { v0 = ov; i0 = oi; }
            }
            if (t == 0) { pool_s[be] = v0; pool_i[be] = i0; }
        }
        __syncthreads();
    }

    if (t < KK) { top_s[q * 64 + t] = win_s[t]; top_i[q * 64 + t] = win_i[t]; }
    else        { top_s[q * 64 + t] = -1e30f;   top_i[q * 64 + t] = 0; }
}

// ---------------- vote: class histogram, normalize, write preds + targets ----------------
__global__ __launch_bounds__(256) void knn_vote(
    const float* __restrict__ top_s, const int* __restrict__ top_i,
    const int* __restrict__ labels, const int* __restrict__ targets,
    float* __restrict__ out)
{
    const int q = blockIdx.x;
    const int t = threadIdx.x;
    __shared__ float hist[CC];
    __shared__ float ssum;

    for (int c = t; c < CC; c += 256) hist[c] = 0.f;
    if (t == 0) ssum = 0.f;
    __syncthreads();

    if (t < KK) {
        float s = top_s[q * 64 + t];
        int   idx = top_i[q * 64 + t];
        if (s > -1e29f) {
            int lab = labels[idx];
            atomicAdd(&hist[lab], s);
            atomicAdd(&ssum, s);
        }
    }
    __syncthreads();

    float denom = ssum;
    if (denom == 0.f) denom = 1.f;
    float inv = 1.f / denom;
    for (int c = t; c < CC; c += 256)
        out[(size_t)q * CC + c] = hist[c] * inv;
    if (t == 0)
        out[(size_t)QN * CC + q] = (float)targets[q];
}

// ---------------- host launch ----------------
extern "C" void kernel_launch(void* const* d_in, const int* in_sizes, int n_in,
                              void* d_out, int out_size, void* d_ws, size_t ws_size,
                              hipStream_t stream) {
    const float* samples = (const float*)d_in[0];   // [QN][DD]
    const int*   targets = (const int*)d_in[1];     // [QN]
    const float* train   = (const float*)d_in[2];   // [NN][DD]
    const int*   labels  = (const int*)d_in[3];     // [NN]
    float* out = (float*)d_out;

    char* ws = (char*)d_ws;
    short* Ahi = (short*)ws;                                     // 4MB
    short* Alo = Ahi + (size_t)QN * DD;                          // 4MB
    short* Bhi = (short*)(ws + (16 << 20));                      // 195.5MB
    size_t bm_off = (size_t)(16 << 20) + 2 * (size_t)BROWS * DD * 2;
    float* bm_s = (float*)(ws + bm_off);                         // ≈ 6.1MB
    int*   bm_i = (int*)(ws + bm_off + (8 << 20));               // ≈ 6.1MB
    float* top_s = (float*)(ws + bm_off + (16 << 20));           // 512KB
    int*   top_i = (int*)(ws + bm_off + (17 << 20));             // 512KB
    float* scores = (float*)(ws + bm_off + (18 << 20));          // ≈ 820MB

    knn_convert<<<QN,    256, 0, stream>>>(samples, Ahi, Alo, QN, 1);
    knn_convert<<<BROWS, 256, 0, stream>>>(train,   Bhi, nullptr, NN, 0);

    dim3 grid(QN / BMT, GY);    // (8, 391); swizzle in-kernel maps to XCD bands
    knn_gemm<<<grid, 512, 0, stream>>>(Ahi, Alo, Bhi, scores, bm_s, bm_i);

    knn_merge<<<QN, 64, 0, stream>>>(scores, bm_s, bm_i, top_s, top_i);
    knn_vote<<<QN, 256, 0, stream>>>(top_s, top_i, labels, targets, out);
}

// Round 4
// 1339.992 us; speedup vs baseline: 1.3022x; 1.2036x over previous
//
#include <hip/hip_runtime.h>
#include <hip/hip_bf16.h>

// Problem constants
#define QN    2048
#define NN    100000
#define DD    1024
#define CC    1000
#define KK    50
#define BROWS 100096   // NN padded to multiple of 256
#define NBLK  782      // merge granularity: BROWS / 128
#define BMT   256      // gemm tile M (q rows)
#define BNT   256      // gemm tile N (gallery cols)
#define BKT   32       // k per tile
#define KT    (DD / BKT)     // 32 k-tiles
#define GY    (BROWS / BNT)  // 391

typedef _Float16 f16x8 __attribute__((ext_vector_type(8)));
typedef float f32x4  __attribute__((ext_vector_type(4)));

__device__ __forceinline__ short f2h(float x) {
    _Float16 h = (_Float16)x;                    // RN
    return (short)__builtin_bit_cast(unsigned short, h);
}

// ---------------- convert: fp32 -> fp16 ----------------
// Single-term fp16: score error dominated by delta-b term (~0.8e-5); adding an
// A-residual stream only brings 1.1e-5 -> 0.8e-5 — not worth 50% more MFMA.
__global__ __launch_bounds__(256) void knn_convert(
    const float* __restrict__ src, short* __restrict__ hi, int rows_valid)
{
    const int n  = blockIdx.x;
    const int k4 = threadIdx.x << 2;
    float4 v = make_float4(0.f, 0.f, 0.f, 0.f);
    if (n < rows_valid)
        v = *reinterpret_cast<const float4*>(&src[(size_t)n * DD + k4]);
    *reinterpret_cast<short4*>(&hi[(size_t)n * DD + k4]) =
        make_short4(f2h(v.x), f2h(v.y), f2h(v.z), f2h(v.w));
}

// ---------------- MFMA GEMM, 256x256 tile, 3-ring + 2-phase interleave ----------------
// 8 waves (2M x 4N), per-wave 128x64 output = acc[8][4] of 16x16 frags, fp16 A*B.
// Per K-tile (BK=32): 2 phases x {ds_read subtile | issue 2 GLs for tile t+2 |
//   s_barrier | lgkmcnt(0)+sched_barrier | setprio(1) 16 MFMA setprio(0) | barrier}.
// Counted s_waitcnt vmcnt(4) folded into phase-1 POST (t+1 retired, t+2 in
// flight) — never drained to 0 in steady state (T3+T4). 4 barriers/tile.
// Chunk-XOR LDS swizzle: slot chunk cs holds data chunk cs^((row>>1)&3).
#define GL(gptr, ldsptr) __builtin_amdgcn_global_load_lds(                    \
    (const __attribute__((address_space(1))) void*)(gptr),                    \
    (__attribute__((address_space(3))) void*)(ldsptr), 16, 0, 0)

__global__ __launch_bounds__(512, 2) void knn_gemm(
    const short* __restrict__ Ahi, const short* __restrict__ Bhi,
    float* __restrict__ out, float* __restrict__ bm_s, int* __restrict__ bm_i)
{
    __shared__ short ring[3][2][256][32];   // [slot][stream 0=A,1=B][row][k]
    __shared__ float red_s[4][256];
    __shared__ int   red_i[4][256];

    const int tid  = threadIdx.x;
    const int lane = tid & 63;
    const int w    = tid >> 6;           // 0..7
    const int wm   = (w >> 2) * 128;     // wave M offset
    const int wn   = (w & 3) * 64;       // wave N offset

    // bijective XCD swizzle: 3128 blocks = 8 XCDs * 391; XCD k gets a
    // contiguous band of c-panels (vy) with all q-slices (vx) -> B L2 reuse.
    const int lin = (int)blockIdx.x + 8 * (int)blockIdx.y;   // gridDim.x == 8
    const int g   = (lin & 7) * GY + (lin >> 3);
    const int vx  = g & 7;
    const int vy  = g >> 3;
    const int q0  = vx * BMT;
    const int c0  = vy * BNT;

    const int srow = w * 16 + (lane >> 2);                    // staging row 0..127 (+128 for GL#2)
    const int kb   = (((lane & 3) ^ ((lane >> 3) & 3)) * 16); // swizzled source chunk bytes
    const int fr   = lane & 15;
    const int fq   = lane >> 4;
    const int cx   = (fq ^ ((fr >> 1) & 3)) * 8;              // swizzled read chunk (shorts)

    f32x4 acc[8][4];
    #pragma unroll
    for (int i = 0; i < 8; ++i)
        #pragma unroll
        for (int j = 0; j < 4; ++j)
            acc[i][j] = (f32x4){0.f, 0.f, 0.f, 0.f};

    const size_t rowb = (size_t)DD * 2;
    const size_t gA   = (size_t)(q0 + srow) * rowb + kb;
    const size_t gA2  = gA + 128 * rowb;
    const size_t gB   = (size_t)(c0 + srow) * rowb + kb;
    const size_t gB2  = gB + 128 * rowb;
    char* ringc      = (char*)&ring[0][0][0][0];
    const int  w16b  = (w * 16) * 64;    // wave-uniform LDS staging byte offset

#define STAGE_A(t2, sl) do {                                                  \
    const size_t ko = (size_t)(t2) * (BKT * 2);                               \
    char* L = ringc + ((sl) * 2 + 0) * (256 * 64) + w16b;                     \
    GL((const char*)Ahi + gA  + ko, L);                                       \
    GL((const char*)Ahi + gA2 + ko, L + 128 * 64);                            \
} while (0)
#define STAGE_B(t2, sl) do {                                                  \
    const size_t ko = (size_t)(t2) * (BKT * 2);                               \
    char* L = ringc + ((sl) * 2 + 1) * (256 * 64) + w16b;                     \
    GL((const char*)Bhi + gB  + ko, L);                                       \
    GL((const char*)Bhi + gB2 + ko, L + 128 * 64);                            \
} while (0)

#define DS_A(i) (*reinterpret_cast<const f16x8*>(&Ahs[wm + (i) * 16 + fr][cx]))
#define DS_B(j) (*reinterpret_cast<const f16x8*>(&Bhs[wn + (j) * 16 + fr][cx]))

#define MFMA16(BASE)                                                          \
    __builtin_amdgcn_s_setprio(1);                                            \
    _Pragma("unroll")                                                         \
    for (int j = 0; j < 4; ++j) {                                             \
        acc[(BASE) + 0][j] = __builtin_amdgcn_mfma_f32_16x16x32_f16(a0, bh[j], acc[(BASE) + 0][j], 0, 0, 0); \
        acc[(BASE) + 1][j] = __builtin_amdgcn_mfma_f32_16x16x32_f16(a1, bh[j], acc[(BASE) + 1][j], 0, 0, 0); \
        acc[(BASE) + 2][j] = __builtin_amdgcn_mfma_f32_16x16x32_f16(a2, bh[j], acc[(BASE) + 2][j], 0, 0, 0); \
        acc[(BASE) + 3][j] = __builtin_amdgcn_mfma_f32_16x16x32_f16(a3, bh[j], acc[(BASE) + 3][j], 0, 0, 0); \
    }                                                                         \
    __builtin_amdgcn_s_setprio(0);

#define PHASE_SYNC_PRE()                                                      \
    __builtin_amdgcn_s_barrier();                                             \
    asm volatile("s_waitcnt lgkmcnt(0)" ::: "memory");                        \
    __builtin_amdgcn_sched_barrier(0);

    // prologue: tiles 0,1 staged; vmcnt(4) = tile0's 4 done, tile1's in flight
    STAGE_A(0, 0); STAGE_B(0, 0);
    STAGE_A(1, 1); STAGE_B(1, 1);
    asm volatile("s_waitcnt vmcnt(4)" ::: "memory");
    __builtin_amdgcn_s_barrier();
    __builtin_amdgcn_sched_barrier(0);

    int slot = 0;
    for (int t = 0; t < KT; ++t) {
        const short (*Ahs)[32] = ring[slot][0];
        const short (*Bhs)[32] = ring[slot][1];
        const int  s2 = (slot + 2 >= 3) ? slot - 1 : slot + 2;
        const bool pf = (t + 2 < KT);

        f16x8 bh[4];
        // ---- phase 0: B frags + A rows 0-3 ---- (8 ds_reads, 2 GLs)
        bh[0] = DS_B(0); bh[1] = DS_B(1); bh[2] = DS_B(2); bh[3] = DS_B(3);
        f16x8 a0 = DS_A(0), a1 = DS_A(1), a2 = DS_A(2), a3 = DS_A(3);
        if (pf) STAGE_A(t + 2, s2);
        PHASE_SYNC_PRE();
        MFMA16(0);
        __builtin_amdgcn_sched_barrier(0);
        __builtin_amdgcn_s_barrier();

        // ---- phase 1: A rows 4-7 ---- (4 ds_reads, 2 GLs)
        a0 = DS_A(4); a1 = DS_A(5); a2 = DS_A(6); a3 = DS_A(7);
        if (pf) STAGE_B(t + 2, s2);
        PHASE_SYNC_PRE();
        MFMA16(4);
        __builtin_amdgcn_sched_barrier(0);

        // ---- tile end (folded into phase-1 POST): counted wait, never 0 in steady ----
        if (pf)                asm volatile("s_waitcnt vmcnt(4)" ::: "memory");
        else if (t + 1 < KT)   asm volatile("s_waitcnt vmcnt(0)" ::: "memory");
        __builtin_amdgcn_s_barrier();
        __builtin_amdgcn_sched_barrier(0);
        slot = (slot + 1 >= 3) ? 0 : slot + 1;
    }
#undef STAGE_A
#undef STAGE_B

    // epilogue: D layout col=lane&15, row=(lane>>4)*4+reg  [m89-verified]
    // scores write (padded cols -> -1e30) + per-row max at 128-col granularity
    #pragma unroll
    for (int i = 0; i < 8; ++i) {
        const int lrow = wm + i * 16 + fq * 4;   // +r
        const int qrow = q0 + lrow;
        float rv[4]; int rc[4];
        #pragma unroll
        for (int r = 0; r < 4; ++r) { rv[r] = -3e30f; rc[r] = 0; }
        #pragma unroll
        for (int j = 0; j < 4; ++j) {
            const int col = c0 + wn + j * 16 + fr;
            const bool ok = (col < NN);
            float* dst = &out[(size_t)qrow * BROWS + col];
            #pragma unroll
            for (int r = 0; r < 4; ++r) {
                float v = ok ? acc[i][j][r] : -1e30f;
                dst[r * (size_t)BROWS] = v;
                if (v > rv[r]) { rv[r] = v; rc[r] = col; }   // ascending j: ties keep smaller col
            }
        }
        #pragma unroll
        for (int r = 0; r < 4; ++r) {
            float v = rv[r]; int c = rc[r];
            #pragma unroll
            for (int m = 1; m <= 8; m <<= 1) {               // reduce across fr (16-lane group)
                float ov = __shfl_xor(v, m);
                int   oc = __shfl_xor(c, m);
                if (ov > v || (ov == v && oc < c)) { v = ov; c = oc; }
            }
            if (fr == 0) {
                red_s[w & 3][lrow + r] = v;
                red_i[w & 3][lrow + r] = c;
            }
        }
    }
    __syncthreads();
    {
        // 512 threads: half 0 combines wn-groups {0,1} (cols c0..c0+127) -> bm[2*vy],
        //              half 1 combines {2,3} (cols c0+128..255) -> bm[2*vy+1]
        const int row  = tid & 255;
        const int half = tid >> 8;
        float v0 = red_s[2 * half][row],     v1 = red_s[2 * half + 1][row];
        int   i0 = red_i[2 * half][row],     i1 = red_i[2 * half + 1][row];
        bool take1 = (v1 > v0) || (v1 == v0 && i1 < i0);
        bm_s[(size_t)(q0 + row) * NBLK + vy * 2 + half] = take1 ? v1 : v0;
        bm_i[(size_t)(q0 + row) * NBLK + vy * 2 + half] = take1 ? i1 : i0;
    }
}

// ---------------- merge: per-query top-50 from 782 block maxima ----------------
__global__ __launch_bounds__(64) void knn_merge(
    float* __restrict__ sc,
    const float* __restrict__ bm_s, const int* __restrict__ bm_i,
    float* __restrict__ top_s, int* __restrict__ top_i)
{
    const int q = blockIdx.x;
    const int t = threadIdx.x;

    __shared__ float pool_s[NBLK];
    __shared__ int   pool_i[NBLK];
    __shared__ float win_s[KK];
    __shared__ int   win_i[KK];

    float* row = sc + (size_t)q * BROWS;

    for (int e = t; e < NBLK; e += 64) {
        pool_s[e] = bm_s[(size_t)q * NBLK + e];
        pool_i[e] = bm_i[(size_t)q * NBLK + e];
    }
    __syncthreads();

    for (int r = 0; r < KK; ++r) {
        float bs = -3e30f; int be = 0;
        for (int e = t; e < NBLK; e += 64) {
            float v = pool_s[e];
            if (v > bs) { bs = v; be = e; }
        }
        #pragma unroll
        for (int m = 32; m; m >>= 1) {
            float ov = __shfl_xor(bs, m);
            int   oe = __shfl_xor(be, m);
            if (ov > bs || (ov == bs && oe < be)) { bs = ov; be = oe; }
        }
        if (t == 0) {
            win_s[r] = bs;
            win_i[r] = pool_i[be];
            row[pool_i[be]] = -1e30f;            // mark taken
        }
        __syncthreads();

        {   // rescan winning 128-col slice
            const int base = be * 128;
            float v0 = row[base + t], v1 = row[base + 64 + t];
            int   i0 = base + t,      i1 = base + 64 + t;
            if (v1 > v0) { v0 = v1; i0 = i1; }
            #pragma unroll
            for (int m = 32; m; m >>= 1) {
                float ov = __shfl_xor(v0, m);
                int   oi = __shfl_xor(i0, m);
                if (ov > v0 || (ov == v0 && oi < i0)) { v0 = ov; i0 = oi; }
            }
            if (t == 0) { pool_s[be] = v0; pool_i[be] = i0; }
        }
        __syncthreads();
    }

    if (t < KK) { top_s[q * 64 + t] = win_s[t]; top_i[q * 64 + t] = win_i[t]; }
    else        { top_s[q * 64 + t] = -1e30f;   top_i[q * 64 + t] = 0; }
}

// ---------------- vote: class histogram, normalize, write preds + targets ----------------
__global__ __launch_bounds__(256) void knn_vote(
    const float* __restrict__ top_s, const int* __restrict__ top_i,
    const int* __restrict__ labels, const int* __restrict__ targets,
    float* __restrict__ out)
{
    const int q = blockIdx.x;
    const int t = threadIdx.x;
    __shared__ float hist[CC];
    __shared__ float ssum;

    for (int c = t; c < CC; c += 256) hist[c] = 0.f;
    if (t == 0) ssum = 0.f;
    __syncthreads();

    if (t < KK) {
        float s = top_s[q * 64 + t];
        int   idx = top_i[q * 64 + t];
        if (s > -1e29f) {
            int lab = labels[idx];
            atomicAdd(&hist[lab], s);
            atomicAdd(&ssum, s);
        }
    }
    __syncthreads();

    float denom = ssum;
    if (denom == 0.f) denom = 1.f;
    float inv = 1.f / denom;
    for (int c = t; c < CC; c += 256)
        out[(size_t)q * CC + c] = hist[c] * inv;
    if (t == 0)
        out[(size_t)QN * CC + q] = (float)targets[q];
}

// ---------------- host launch ----------------
extern "C" void kernel_launch(void* const* d_in, const int* in_sizes, int n_in,
                              void* d_out, int out_size, void* d_ws, size_t ws_size,
                              hipStream_t stream) {
    const float* samples = (const float*)d_in[0];   // [QN][DD]
    const int*   targets = (const int*)d_in[1];     // [QN]
    const float* train   = (const float*)d_in[2];   // [NN][DD]
    const int*   labels  = (const int*)d_in[3];     // [NN]
    float* out = (float*)d_out;

    char* ws = (char*)d_ws;
    short* Ahi = (short*)ws;                                     // 4MB
    short* Bhi = (short*)(ws + (16 << 20));                      // 195.5MB
    size_t bm_off = (size_t)(16 << 20) + 2 * (size_t)BROWS * DD * 2;
    float* bm_s = (float*)(ws + bm_off);                         // ≈ 6.1MB
    int*   bm_i = (int*)(ws + bm_off + (8 << 20));               // ≈ 6.1MB
    float* top_s = (float*)(ws + bm_off + (16 << 20));           // 512KB
    int*   top_i = (int*)(ws + bm_off + (17 << 20));             // 512KB
    float* scores = (float*)(ws + bm_off + (18 << 20));          // ≈ 820MB

    knn_convert<<<QN,    256, 0, stream>>>(samples, Ahi, QN);
    knn_convert<<<BROWS, 256, 0, stream>>>(train,   Bhi, NN);

    dim3 grid(QN / BMT, GY);    // (8, 391); swizzle in-kernel maps to XCD bands
    knn_gemm<<<grid, 512, 0, stream>>>(Ahi, Bhi, scores, bm_s, bm_i);

    knn_merge<<<QN, 64, 0, stream>>>(scores, bm_s, bm_i, top_s, top_i);
    knn_vote<<<QN, 256, 0, stream>>>(top_s, top_i, labels, targets, out);
}